// Round 8
// baseline (3782.526 us; speedup 1.0000x reference)
//
#include <hip/hip_runtime.h>
#include <hip/hip_bf16.h>
#include <math.h>

#define T_STEPS 256
#define NBLK    128
#define SLAB_SH 262144        // shorts per xpf time-slab (= NBLK*64*32)

typedef __attribute__((ext_vector_type(8))) short short8_t;   // 8 bf16
typedef __attribute__((ext_vector_type(4))) float f32x4;
typedef __attribute__((ext_vector_type(4))) unsigned short ushort4_t;

__device__ __forceinline__ unsigned short f2bf(float v) {
    __hip_bfloat16 h = __float2bfloat16(v);
    return *reinterpret_cast<unsigned short*>(&h);
}
__device__ __forceinline__ float bf2f(unsigned short u) {
    __hip_bfloat16 h;
    *reinterpret_cast<unsigned short*>(&h) = u;
    return __bfloat162float(h);
}

// ---------------------------------------------------------------------------
// pack_gate: gate-weight B-fragments (unchanged from round 7).
// ---------------------------------------------------------------------------
__global__ __launch_bounds__(256) void pack_gate(
    const float* __restrict__ Wi, const float* __restrict__ Wf,
    const float* __restrict__ Wo, const float* __restrict__ Wc,
    unsigned short* __restrict__ PGh, unsigned short* __restrict__ PGl)
{
    int ng = blockIdx.y;
    int slot = blockIdx.x * 4 + (threadIdx.x >> 6);   // 0..63
    int nt = slot >> 5, ks = slot & 31;
    int lane = threadIdx.x & 63;
    int n = lane & 15, g = n >> 2;
    int j = 8 * ng + nt * 4 + (n & 3);
    int k0 = ks * 32 + (lane >> 4) * 8;
    const float* W = (g == 0) ? Wi : (g == 1) ? Wf : (g == 2) ? Wo : Wc;
    const float* src = W + (size_t)j * 1024 + k0;

    union { short8_t v; unsigned short u[8]; } hi, lo;
#pragma unroll
    for (int e = 0; e < 8; ++e) {
        float v = src[e];
        hi.u[e] = f2bf(v);
        lo.u[e] = f2bf(v - bf2f(hi.u[e]));
    }
    size_t o = (((size_t)(ng * 2 + nt) * 32 + ks) * 64 + lane) * 8;
    *(short8_t*)(PGh + o) = hi.v;
    *(short8_t*)(PGl + o) = lo.v;
}

// ---------------------------------------------------------------------------
// pack_wout_frag: standard B-fragments of Wout for the post-pass.
// PF[((nt*32+ks)*64+lane)*8+e] = Wout[nt*16+(lane&15)][ks*32+(lane>>4)*8+e]
// grid (64, 8), block 256.
// ---------------------------------------------------------------------------
__global__ __launch_bounds__(256) void pack_wout_frag(
    const float* __restrict__ Wout,
    unsigned short* __restrict__ PFh, unsigned short* __restrict__ PFl)
{
    int nt = blockIdx.x;
    int ks = blockIdx.y * 4 + (threadIdx.x >> 6);
    int lane = threadIdx.x & 63;
    int j = nt * 16 + (lane & 15);
    int k0 = ks * 32 + (lane >> 4) * 8;
    const float* src = Wout + (size_t)j * 1024 + k0;

    union { short8_t v; unsigned short u[8]; } hi, lo;
#pragma unroll
    for (int e = 0; e < 8; ++e) {
        float v = src[e];
        hi.u[e] = f2bf(v);
        lo.u[e] = f2bf(v - bf2f(hi.u[e]));
    }
    size_t o = (((size_t)nt * 32 + ks) * 64 + lane) * 8;
    *(short8_t*)(PFh + o) = hi.v;
    *(short8_t*)(PFl + o) = lo.v;
}

// ---------------------------------------------------------------------------
// trans_h0f: h0[b][k] -> A-fragment layout [copy][mt][ks][lane][8] bf16 hi/lo
// ---------------------------------------------------------------------------
__global__ __launch_bounds__(256) void trans_h0f(
    const float* __restrict__ h0, unsigned short* __restrict__ hA)
{
    int id = blockIdx.x * 256 + threadIdx.x;   // [0, 16384)
    int lane = id & 63;
    int ks = (id >> 6) & 31;
    int mt = (id >> 11) & 3;
    int copy = id >> 13;
    int b = mt * 16 + (lane & 15);
    int k = ks * 32 + (lane >> 4) * 8;
    const float* src = h0 + (size_t)b * 1024 + k;

    union { short8_t v; unsigned short u[8]; } o;
#pragma unroll
    for (int e = 0; e < 8; ++e) {
        float v = src[e];
        unsigned short hb = f2bf(v);
        o.u[e] = (copy == 0) ? hb : f2bf(v - bf2f(hb));
    }
    *(short8_t*)(hA + (size_t)id * 8) = o.v;
}

// ---------------------------------------------------------------------------
// xproj bf16 MFMA GEMM; epilogue scatters to xpf[t][ng(128)][b][jj(8)][g(4)].
// ---------------------------------------------------------------------------
__global__ __launch_bounds__(256) void xproj_mfma(
    const float* __restrict__ X,
    const float* __restrict__ W0, const float* __restrict__ W1,
    const float* __restrict__ W2, const float* __restrict__ W3,
    unsigned short* __restrict__ xpf)
{
    __shared__ short8_t As[4 * 128];
    __shared__ short8_t Bs[4 * 128];

    const int bm = blockIdx.x;
    const int bn = blockIdx.y;
    const float* W = (bn < 8) ? W0 : (bn < 16) ? W1 : (bn < 24) ? W2 : W3;
    const int jbase = (bn & 7) * 128;
    const int m0 = bm * 128;

    const int tid  = threadIdx.x;
    const int lane = tid & 63;
    const int wave = tid >> 6;
    const int wm = wave >> 1, wn = wave & 1;
    const int q  = lane >> 4;
    const int lr = lane & 15;

    f32x4 acc[4][4];
#pragma unroll
    for (int i = 0; i < 4; ++i)
#pragma unroll
        for (int j = 0; j < 4; ++j) acc[i][j] = (f32x4){0.f, 0.f, 0.f, 0.f};

    for (int k0 = 0; k0 < 1024; k0 += 32) {
#pragma unroll
        for (int ss = 0; ss < 2; ++ss) {
            int s  = tid + ss * 256;
            int kg = s & 3, r = s >> 2;
            const float* xa = X + (size_t)(m0 + r) * 1024 + k0 + kg * 8;
            const float* wb = W + (size_t)(jbase + r) * 1024 + k0 + kg * 8;
            float4 a0 = *(const float4*)(xa);
            float4 a1 = *(const float4*)(xa + 4);
            float4 b0 = *(const float4*)(wb);
            float4 b1 = *(const float4*)(wb + 4);
            union { short8_t v; unsigned short u[8]; } ua, ub;
            float af[8] = {a0.x,a0.y,a0.z,a0.w,a1.x,a1.y,a1.z,a1.w};
            float bf[8] = {b0.x,b0.y,b0.z,b0.w,b1.x,b1.y,b1.z,b1.w};
#pragma unroll
            for (int e = 0; e < 8; ++e) {
                ua.u[e] = f2bf(af[e]);
                ub.u[e] = f2bf(bf[e]);
            }
            As[kg * 128 + r] = ua.v;
            Bs[kg * 128 + r] = ub.v;
        }
        __syncthreads();

        short8_t a[4], b[4];
#pragma unroll
        for (int mi = 0; mi < 4; ++mi)
            a[mi] = As[q * 128 + wm * 64 + mi * 16 + lr];
#pragma unroll
        for (int nj = 0; nj < 4; ++nj)
            b[nj] = Bs[q * 128 + wn * 64 + nj * 16 + lr];
#pragma unroll
        for (int mi = 0; mi < 4; ++mi)
#pragma unroll
            for (int nj = 0; nj < 4; ++nj)
                acc[mi][nj] = __builtin_amdgcn_mfma_f32_16x16x32_bf16(
                    a[mi], b[nj], acc[mi][nj], 0, 0, 0);
        __syncthreads();
    }

#pragma unroll
    for (int mi = 0; mi < 4; ++mi)
#pragma unroll
        for (int nj = 0; nj < 4; ++nj)
#pragma unroll
            for (int r = 0; r < 4; ++r) {
                int m = m0 + wm * 64 + mi * 16 + q * 4 + r;
                int n = bn * 128 + wn * 64 + nj * 16 + lr;
                int tt = m >> 6, bb = m & 63;
                int g = n >> 10, jc = n & 1023;
                xpf[(((size_t)tt * NBLK + (jc >> 3)) * 64 + bb) * 32 + (jc & 7) * 4 + g]
                    = f2bf(acc[mi][nj][r]);
            }
}

// ---------------------------------------------------------------------------
// 2-level arrive + direct master poll (no flag rebroadcast level).
// ---------------------------------------------------------------------------
__device__ __forceinline__ void arrive_wait(unsigned* bar, int ng, unsigned epoch)
{
    __syncthreads();
    if (threadIdx.x == 0) {
        asm volatile("s_waitcnt vmcnt(0)" ::: "memory");
        unsigned* scnt = bar + (ng >> 3) * 32;               // 16 stripes x 8
        unsigned old = __hip_atomic_fetch_add(scnt, 1u,
                           __ATOMIC_RELAXED, __HIP_MEMORY_SCOPE_SYSTEM);
        if (old == 8u * epoch - 1u)
            __hip_atomic_fetch_add(bar + 512, 1u,
                           __ATOMIC_RELAXED, __HIP_MEMORY_SCOPE_SYSTEM);
        while (__hip_atomic_load(bar + 512,
                   __ATOMIC_RELAXED, __HIP_MEMORY_SCOPE_SYSTEM) < 16u * epoch)
            __builtin_amdgcn_s_sleep(1);
    }
    __syncthreads();
}

// ---------------------------------------------------------------------------
// Persistent MFMA LSTM loop (gates only; out deferred to post-pass).
// h(t+1) archived into consumed xpf slab t (bypass stores). Step t reads
// h(t) from slab t-1 (t=0: hA). Pre-loop barrier protects slab-0 reuse.
// ---------------------------------------------------------------------------
__global__ __launch_bounds__(512, 1) void lstm_loop7(
    unsigned short* __restrict__ xpf,
    const unsigned short* __restrict__ PGh, const unsigned short* __restrict__ PGl,
    const float* __restrict__ c0,
    const unsigned short* __restrict__ hA,
    unsigned* __restrict__ bar)
{
    __shared__ f32x4 red[8][8][64];    // [wave][mt*2+nt][lane]  64 KB
    __shared__ f32x4 redF[8][64];      //                         8 KB
    __shared__ unsigned short hsc[64 * 2 * 8];  // [b][cp][jj]    2 KB

    const int tid  = threadIdx.x;
    const int lane = tid & 63;
    const int kq   = tid >> 6;
    const int ng   = blockIdx.x;        // 0..127

    // ---- persistent gate B fragments in registers ----
    short8_t bgh[2][4], bgl[2][4];
#pragma unroll
    for (int i = 0; i < 4; ++i) {
        int ks = 4 * kq + i;
#pragma unroll
        for (int nt = 0; nt < 2; ++nt) {
            size_t og = (((size_t)(ng * 2 + nt) * 32 + ks) * 64 + lane) * 8;
            bgh[nt][i] = *(const short8_t*)(PGh + og);
            bgl[nt][i] = *(const short8_t*)(PGl + og);
        }
    }

    // combine identity: all 512 threads, b = tid>>3, jj = tid&7
    const int cb = tid >> 3, cjj = tid & 7;
    float c_reg = c0[(size_t)cb * 1024 + 8 * ng + cjj];
    ushort4_t xq = *(const ushort4_t*)(xpf + ((size_t)ng * 64 + cb) * 32 + cjj * 4);

    // h-store address pieces: j-range [8ng,8ng+8)
    const int ks2  = ng >> 2;
    const int l2hi = (ng & 3) << 4;

    arrive_wait(bar, ng, 1u);   // all initial xq reads done before slab-0 writes

#pragma unroll 1
    for (int t = 0; t < T_STEPS; ++t) {
        const unsigned short* hc = (t == 0) ? hA : xpf + (size_t)(t - 1) * SLAB_SH;
        unsigned short*       hn = xpf + (size_t)t * SLAB_SH;

        f32x4 acc[4][2];
#pragma unroll
        for (int mt = 0; mt < 4; ++mt) {
            acc[mt][0] = (f32x4){0.f, 0.f, 0.f, 0.f};
            acc[mt][1] = (f32x4){0.f, 0.f, 0.f, 0.f};
        }

#pragma unroll
        for (int i = 0; i < 4; ++i) {
            const int ks = 4 * kq + i;
            short8_t ah[4], al[4];
#pragma unroll
            for (int mt = 0; mt < 4; ++mt) {
                int off = ((mt * 32 + ks) * 64 + lane) * 8;
                union { short8_t v; unsigned long long q[2]; } uh, ul;
                const unsigned long long* ph = (const unsigned long long*)(hc + off);
                const unsigned long long* pl = (const unsigned long long*)(hc + 65536 + off);
                uh.q[0] = __hip_atomic_load(ph,     __ATOMIC_RELAXED, __HIP_MEMORY_SCOPE_SYSTEM);
                uh.q[1] = __hip_atomic_load(ph + 1, __ATOMIC_RELAXED, __HIP_MEMORY_SCOPE_SYSTEM);
                ul.q[0] = __hip_atomic_load(pl,     __ATOMIC_RELAXED, __HIP_MEMORY_SCOPE_SYSTEM);
                ul.q[1] = __hip_atomic_load(pl + 1, __ATOMIC_RELAXED, __HIP_MEMORY_SCOPE_SYSTEM);
                ah[mt] = uh.v;
                al[mt] = ul.v;
            }
#pragma unroll
            for (int mt = 0; mt < 4; ++mt) {
                acc[mt][0] = __builtin_amdgcn_mfma_f32_16x16x32_bf16(ah[mt], bgh[0][i], acc[mt][0], 0,0,0);
                acc[mt][1] = __builtin_amdgcn_mfma_f32_16x16x32_bf16(ah[mt], bgh[1][i], acc[mt][1], 0,0,0);
                acc[mt][0] = __builtin_amdgcn_mfma_f32_16x16x32_bf16(al[mt], bgh[0][i], acc[mt][0], 0,0,0);
                acc[mt][1] = __builtin_amdgcn_mfma_f32_16x16x32_bf16(al[mt], bgh[1][i], acc[mt][1], 0,0,0);
                acc[mt][0] = __builtin_amdgcn_mfma_f32_16x16x32_bf16(ah[mt], bgl[0][i], acc[mt][0], 0,0,0);
                acc[mt][1] = __builtin_amdgcn_mfma_f32_16x16x32_bf16(ah[mt], bgl[1][i], acc[mt][1], 0,0,0);
            }
        }

        // ---- K-reduction across 8 waves (8 tiles) ----
#pragma unroll
        for (int mt = 0; mt < 4; ++mt) {
            red[kq][mt * 2 + 0][lane] = acc[mt][0];
            red[kq][mt * 2 + 1][lane] = acc[mt][1];
        }
        __syncthreads();
        {
            f32x4 s = red[0][kq][lane];
#pragma unroll
            for (int q = 1; q < 8; ++q) s += red[q][kq][lane];
            redF[kq][lane] = s;
        }
        __syncthreads();

        // ---- combine (all 512 threads): gates -> c,h ----
        {
            const int mt  = cb >> 4;
            const int lnb = (cb & 12) << 2;
            const int rg  = cb & 3;
            const int nt  = cjj >> 2;
            float pre0 = redF[mt * 2 + nt][lnb | (0  + (cjj & 3))][rg] + bf2f(xq[0]);
            float pre1 = redF[mt * 2 + nt][lnb | (4  + (cjj & 3))][rg] + bf2f(xq[1]);
            float pre2 = redF[mt * 2 + nt][lnb | (8  + (cjj & 3))][rg] + bf2f(xq[2]);
            float pre3 = redF[mt * 2 + nt][lnb | (12 + (cjj & 3))][rg] + bf2f(xq[3]);
            float gi = 1.f / (1.f + expf(-pre0));
            float gf = 1.f / (1.f + expf(-pre1));
            float go = 1.f / (1.f + expf(-pre2));
            float cn = gf * c_reg + gi * tanhf(pre3);
            c_reg = cn;
            float hv = go * tanhf(cn);
            unsigned short hhi = f2bf(hv);
            unsigned short hlo = f2bf(hv - bf2f(hhi));
            hsc[(cb * 2 + 0) * 8 + cjj] = hhi;
            hsc[(cb * 2 + 1) * 8 + cjj] = hlo;
        }
        __syncthreads();

        // ---- h (bf16 hi/lo) bypass stores into slab t ----
        if (tid < 128) {
            int b = tid >> 1, cp = tid & 1;
            union { short8_t v; unsigned long long q[2]; } u;
            u.v = *(const short8_t*)&hsc[(b * 2 + cp) * 8];
            int elem = (((cp * 4 + (b >> 4)) * 32 + ks2) * 64 + ((b & 15) | l2hi)) * 8;
            __hip_atomic_store((unsigned long long*)(hn + elem),     u.q[0],
                               __ATOMIC_RELAXED, __HIP_MEMORY_SCOPE_SYSTEM);
            __hip_atomic_store((unsigned long long*)(hn + elem + 4), u.q[1],
                               __ATOMIC_RELAXED, __HIP_MEMORY_SCOPE_SYSTEM);
        }

        // ---- xq prefetch for t+1 (flies during the barrier wait) ----
        if (t + 1 < T_STEPS)
            xq = *(const ushort4_t*)(xpf +
                (((size_t)(t + 1) * NBLK + ng) * 64 + cb) * 32 + cjj * 4);

        arrive_wait(bar, ng, (unsigned)(t + 2));
    }
}

// ---------------------------------------------------------------------------
// out_post: out[t] = h(t+1) @ Wout^T from archived slabs. grid 256 (one t),
// block 512 (8 waves); wave w covers n-tiles w*8..w*8+7 in 2 passes of 4.
// Same 3-pass hi/lo math as the old in-loop out.
// ---------------------------------------------------------------------------
__global__ __launch_bounds__(512) void out_post(
    const unsigned short* __restrict__ slabs,
    const unsigned short* __restrict__ PFh, const unsigned short* __restrict__ PFl,
    float* __restrict__ out)
{
    const int t = blockIdx.x;
    const int tid = threadIdx.x, lane = tid & 63, w = tid >> 6;
    const unsigned short* AH = slabs + (size_t)t * SLAB_SH;
    const unsigned short* AL = AH + 65536;

#pragma unroll 1
    for (int p = 0; p < 2; ++p) {
        f32x4 acc[4][4];   // [ntl][mt]
#pragma unroll
        for (int a = 0; a < 4; ++a)
#pragma unroll
            for (int b = 0; b < 4; ++b) acc[a][b] = (f32x4){0.f,0.f,0.f,0.f};

        for (int ks = 0; ks < 32; ++ks) {
            short8_t ah[4], al[4];
#pragma unroll
            for (int mt = 0; mt < 4; ++mt) {
                int off = ((mt * 32 + ks) * 64 + lane) * 8;
                ah[mt] = *(const short8_t*)(AH + off);
                al[mt] = *(const short8_t*)(AL + off);
            }
#pragma unroll
            for (int ntl = 0; ntl < 4; ++ntl) {
                int nt = w * 8 + p * 4 + ntl;
                size_t bo = (((size_t)nt * 32 + ks) * 64 + lane) * 8;
                short8_t bh = *(const short8_t*)(PFh + bo);
                short8_t bl = *(const short8_t*)(PFl + bo);
#pragma unroll
                for (int mt = 0; mt < 4; ++mt) {
                    acc[ntl][mt] = __builtin_amdgcn_mfma_f32_16x16x32_bf16(ah[mt], bh, acc[ntl][mt], 0,0,0);
                    acc[ntl][mt] = __builtin_amdgcn_mfma_f32_16x16x32_bf16(al[mt], bh, acc[ntl][mt], 0,0,0);
                    acc[ntl][mt] = __builtin_amdgcn_mfma_f32_16x16x32_bf16(ah[mt], bl, acc[ntl][mt], 0,0,0);
                }
            }
        }
#pragma unroll
        for (int ntl = 0; ntl < 4; ++ntl)
#pragma unroll
            for (int mt = 0; mt < 4; ++mt)
#pragma unroll
                for (int rr = 0; rr < 4; ++rr) {
                    int b = mt * 16 + (lane >> 4) * 4 + rr;
                    int n = (w * 8 + p * 4 + ntl) * 16 + (lane & 15);
                    out[(size_t)t * 65536 + (size_t)b * 1024 + n] = acc[ntl][mt][rr];
                }
    }
}

// ---------------------------------------------------------------------------
extern "C" void kernel_launch(void* const* d_in, const int* in_sizes, int n_in,
                              void* d_out, int out_size, void* d_ws, size_t ws_size,
                              hipStream_t stream)
{
    const float* x    = (const float*)d_in[0];
    const float* h0   = (const float*)d_in[1];
    const float* c0   = (const float*)d_in[2];
    const float* Wxi  = (const float*)d_in[3];
    const float* Wxf  = (const float*)d_in[4];
    const float* Wxo  = (const float*)d_in[5];
    const float* Wxc  = (const float*)d_in[6];
    const float* Whi  = (const float*)d_in[7];
    const float* Whf  = (const float*)d_in[8];
    const float* Who  = (const float*)d_in[9];
    const float* Whc  = (const float*)d_in[10];
    const float* Wout = (const float*)d_in[11];
    float* out = (float*)d_out;

    const size_t PG_B  = (size_t)NBLK * 2 * 32 * 64 * 8 * 2;   //  8,388,608 each
    const size_t PF_B  = (size_t)64 * 32 * 64 * 8 * 2;         //  2,097,152 each
    const size_t HF_B  = (size_t)2 * 4 * 32 * 64 * 8 * 2;      //    262,144
    const size_t BAR_B = 8192;
    const size_t XPF_B = (size_t)T_STEPS * SLAB_SH * 2;        // 134,217,728

    char* ws = (char*)d_ws;
    unsigned short* PGh = (unsigned short*)ws;  ws += PG_B;
    unsigned short* PGl = (unsigned short*)ws;  ws += PG_B;
    unsigned short* PFh = (unsigned short*)ws;  ws += PF_B;
    unsigned short* PFl = (unsigned short*)ws;  ws += PF_B;
    unsigned short* hA  = (unsigned short*)ws;  ws += HF_B;
    unsigned*       bar = (unsigned*)ws;        ws += BAR_B;
    unsigned short* xpf = (unsigned short*)ws;  ws += XPF_B;

    hipMemsetAsync(bar, 0, BAR_B, stream);
    pack_gate<<<dim3(16, NBLK), 256, 0, stream>>>(Whi, Whf, Who, Whc, PGh, PGl);
    pack_wout_frag<<<dim3(64, 8), 256, 0, stream>>>(Wout, PFh, PFl);
    trans_h0f<<<dim3(64), 256, 0, stream>>>(h0, hA);
    xproj_mfma<<<dim3(128, 32), 256, 0, stream>>>(x, Wxi, Wxf, Wxo, Wxc, xpf);

    lstm_loop7<<<dim3(NBLK), dim3(512), 0, stream>>>(
        xpf, PGh, PGl, c0, hA, bar);

    out_post<<<dim3(T_STEPS), dim3(512), 0, stream>>>(xpf, PFh, PFl, out);
}

// Round 11
// 3603.830 us; speedup vs baseline: 1.0496x; 1.0496x over previous
//
#include <hip/hip_runtime.h>
#include <hip/hip_bf16.h>
#include <math.h>

#define T_STEPS 256
#define NBLK    128

typedef __attribute__((ext_vector_type(8))) short short8_t;   // 8 bf16
typedef __attribute__((ext_vector_type(4))) float f32x4;
typedef __attribute__((ext_vector_type(4))) unsigned short ushort4_t;

__device__ __forceinline__ unsigned short f2bf(float v) {
    __hip_bfloat16 h = __float2bfloat16(v);
    return *reinterpret_cast<unsigned short*>(&h);
}
__device__ __forceinline__ float bf2f(unsigned short u) {
    __hip_bfloat16 h;
    *reinterpret_cast<unsigned short*>(&h) = u;
    return __bfloat162float(h);
}

// ---------------------------------------------------------------------------
// pack_gate: gate-weight B-fragments for 128-block layout, bf16 hi/lo.
// Block ng owns j in [8ng, 8ng+8): 2 n-tiles (nt). Within tile nt, col
// n = lane&15 -> g = n>>2, j = 8ng + nt*4 + (n&3); k = ks*32+(lane>>4)*8+e.
// dst[(((ng*2+nt)*32+ks)*64+lane)*8 + e]
// grid (16, 128), block 256: slot = bx*4 + (tid>>6) = nt*32+ks.
// ---------------------------------------------------------------------------
__global__ __launch_bounds__(256) void pack_gate(
    const float* __restrict__ Wi, const float* __restrict__ Wf,
    const float* __restrict__ Wo, const float* __restrict__ Wc,
    unsigned short* __restrict__ PGh, unsigned short* __restrict__ PGl)
{
    int ng = blockIdx.y;
    int slot = blockIdx.x * 4 + (threadIdx.x >> 6);   // 0..63
    int nt = slot >> 5, ks = slot & 31;
    int lane = threadIdx.x & 63;
    int n = lane & 15, g = n >> 2;
    int j = 8 * ng + nt * 4 + (n & 3);
    int k0 = ks * 32 + (lane >> 4) * 8;
    const float* W = (g == 0) ? Wi : (g == 1) ? Wf : (g == 2) ? Wo : Wc;
    const float* src = W + (size_t)j * 1024 + k0;

    union { short8_t v; unsigned short u[8]; } hi, lo;
#pragma unroll
    for (int e = 0; e < 8; ++e) {
        float v = src[e];
        hi.u[e] = f2bf(v);
        lo.u[e] = f2bf(v - bf2f(hi.u[e]));
    }
    size_t o = (((size_t)(ng * 2 + nt) * 32 + ks) * 64 + lane) * 8;
    *(short8_t*)(PGh + o) = hi.v;
    *(short8_t*)(PGl + o) = lo.v;
}

// ---------------------------------------------------------------------------
// pack_out: compact out-weight frags (8 real cols per block).
// dst[((ng*32+ks)*32 + kb*8 + n)*8 + e] = Wout[8ng+n][ks*32+kb*8+e]
// grid (4, 128), block 256: ks = bx*8 + tid>>5; sl = tid&31.
// ---------------------------------------------------------------------------
__global__ __launch_bounds__(256) void pack_out(
    const float* __restrict__ Wout,
    unsigned short* __restrict__ POh, unsigned short* __restrict__ POl)
{
    int ng = blockIdx.y;
    int ks = blockIdx.x * 8 + (threadIdx.x >> 5);
    int sl = threadIdx.x & 31;
    int kb = sl >> 3, n = sl & 7;
    int j = 8 * ng + n;
    int k0 = ks * 32 + kb * 8;
    const float* src = Wout + (size_t)j * 1024 + k0;

    union { short8_t v; unsigned short u[8]; } hi, lo;
#pragma unroll
    for (int e = 0; e < 8; ++e) {
        float v = src[e];
        hi.u[e] = f2bf(v);
        lo.u[e] = f2bf(v - bf2f(hi.u[e]));
    }
    size_t o = (((size_t)ng * 32 + ks) * 32 + sl) * 8;
    *(short8_t*)(POh + o) = hi.v;
    *(short8_t*)(POl + o) = lo.v;
}

// ---------------------------------------------------------------------------
// trans_h0f: h0[b][k] -> A-fragment layout [copy][mt][ks][lane][8] bf16 hi/lo
// ---------------------------------------------------------------------------
__global__ __launch_bounds__(256) void trans_h0f(
    const float* __restrict__ h0, unsigned short* __restrict__ hA)
{
    int id = blockIdx.x * 256 + threadIdx.x;   // [0, 16384)
    int lane = id & 63;
    int ks = (id >> 6) & 31;
    int mt = (id >> 11) & 3;
    int copy = id >> 13;
    int b = mt * 16 + (lane & 15);
    int k = ks * 32 + (lane >> 4) * 8;
    const float* src = h0 + (size_t)b * 1024 + k;

    union { short8_t v; unsigned short u[8]; } o;
#pragma unroll
    for (int e = 0; e < 8; ++e) {
        float v = src[e];
        unsigned short hb = f2bf(v);
        o.u[e] = (copy == 0) ? hb : f2bf(v - bf2f(hb));
    }
    *(short8_t*)(hA + (size_t)id * 8) = o.v;
}

// ---------------------------------------------------------------------------
// xproj bf16 MFMA GEMM; epilogue scatters to xpf[t][ng(128)][b][jj(8)][g(4)].
// ---------------------------------------------------------------------------
__global__ __launch_bounds__(256) void xproj_mfma(
    const float* __restrict__ X,
    const float* __restrict__ W0, const float* __restrict__ W1,
    const float* __restrict__ W2, const float* __restrict__ W3,
    unsigned short* __restrict__ xpf)
{
    __shared__ short8_t As[4 * 128];
    __shared__ short8_t Bs[4 * 128];

    const int bm = blockIdx.x;
    const int bn = blockIdx.y;
    const float* W = (bn < 8) ? W0 : (bn < 16) ? W1 : (bn < 24) ? W2 : W3;
    const int jbase = (bn & 7) * 128;
    const int m0 = bm * 128;

    const int tid  = threadIdx.x;
    const int lane = tid & 63;
    const int wave = tid >> 6;
    const int wm = wave >> 1, wn = wave & 1;
    const int q  = lane >> 4;
    const int lr = lane & 15;

    f32x4 acc[4][4];
#pragma unroll
    for (int i = 0; i < 4; ++i)
#pragma unroll
        for (int j = 0; j < 4; ++j) acc[i][j] = (f32x4){0.f, 0.f, 0.f, 0.f};

    for (int k0 = 0; k0 < 1024; k0 += 32) {
#pragma unroll
        for (int ss = 0; ss < 2; ++ss) {
            int s  = tid + ss * 256;
            int kg = s & 3, r = s >> 2;
            const float* xa = X + (size_t)(m0 + r) * 1024 + k0 + kg * 8;
            const float* wb = W + (size_t)(jbase + r) * 1024 + k0 + kg * 8;
            float4 a0 = *(const float4*)(xa);
            float4 a1 = *(const float4*)(xa + 4);
            float4 b0 = *(const float4*)(wb);
            float4 b1 = *(const float4*)(wb + 4);
            union { short8_t v; unsigned short u[8]; } ua, ub;
            float af[8] = {a0.x,a0.y,a0.z,a0.w,a1.x,a1.y,a1.z,a1.w};
            float bf[8] = {b0.x,b0.y,b0.z,b0.w,b1.x,b1.y,b1.z,b1.w};
#pragma unroll
            for (int e = 0; e < 8; ++e) {
                ua.u[e] = f2bf(af[e]);
                ub.u[e] = f2bf(bf[e]);
            }
            As[kg * 128 + r] = ua.v;
            Bs[kg * 128 + r] = ub.v;
        }
        __syncthreads();

        short8_t a[4], b[4];
#pragma unroll
        for (int mi = 0; mi < 4; ++mi)
            a[mi] = As[q * 128 + wm * 64 + mi * 16 + lr];
#pragma unroll
        for (int nj = 0; nj < 4; ++nj)
            b[nj] = Bs[q * 128 + wn * 64 + nj * 16 + lr];
#pragma unroll
        for (int mi = 0; mi < 4; ++mi)
#pragma unroll
            for (int nj = 0; nj < 4; ++nj)
                acc[mi][nj] = __builtin_amdgcn_mfma_f32_16x16x32_bf16(
                    a[mi], b[nj], acc[mi][nj], 0, 0, 0);
        __syncthreads();
    }

#pragma unroll
    for (int mi = 0; mi < 4; ++mi)
#pragma unroll
        for (int nj = 0; nj < 4; ++nj)
#pragma unroll
            for (int r = 0; r < 4; ++r) {
                int m = m0 + wm * 64 + mi * 16 + q * 4 + r;
                int n = bn * 128 + wn * 64 + nj * 16 + lr;
                int tt = m >> 6, bb = m & 63;
                int g = n >> 10, jc = n & 1023;
                xpf[(((size_t)tt * NBLK + (jc >> 3)) * 64 + bb) * 32 + (jc & 7) * 4 + g]
                    = f2bf(acc[mi][nj][r]);
            }
}

// ---------------------------------------------------------------------------
// Persistent MFMA LSTM loop, 128 blocks, striped relaxed-SYSTEM barrier
// (16 stripes x 8 + master + 16 replicated flag lines). Proven config.
// Block ng owns j in [8ng, 8ng+8): 32 gate cols (2 n-tiles) + 8 out cols.
// ---------------------------------------------------------------------------
__global__ __launch_bounds__(512, 1) void lstm_loop6(
    const unsigned short* __restrict__ xpf,
    const unsigned short* __restrict__ PGh, const unsigned short* __restrict__ PGl,
    const unsigned short* __restrict__ POh, const unsigned short* __restrict__ POl,
    const float* __restrict__ c0,
    unsigned short* __restrict__ hA, unsigned short* __restrict__ hB,
    float* __restrict__ out,
    unsigned* __restrict__ bar)
{
    __shared__ f32x4 red[8][12][64];    // [wave][mt*3+nc][lane]  96 KB
    __shared__ f32x4 redF[12][64];      //                        12 KB
    __shared__ unsigned short hsc[64 * 2 * 8];  // [b][cp][jj]     2 KB

    const int tid  = threadIdx.x;
    const int lane = tid & 63;
    const int kq   = tid >> 6;
    const int ng   = blockIdx.x;        // 0..127

    // ---- persistent B fragments in registers ----
    short8_t bgh[2][4], bgl[2][4], boh[4], bol[4];
#pragma unroll
    for (int i = 0; i < 4; ++i) {
        int ks = 4 * kq + i;
#pragma unroll
        for (int nt = 0; nt < 2; ++nt) {
            size_t og = (((size_t)(ng * 2 + nt) * 32 + ks) * 64 + lane) * 8;
            bgh[nt][i] = *(const short8_t*)(PGh + og);
            bgl[nt][i] = *(const short8_t*)(PGl + og);
        }
        short8_t zh = {0,0,0,0,0,0,0,0};
        short8_t zl = {0,0,0,0,0,0,0,0};
        if ((lane & 15) < 8) {
            size_t oo = (((size_t)ng * 32 + ks) * 32 + (lane >> 4) * 8 + (lane & 7)) * 8;
            zh = *(const short8_t*)(POh + oo);
            zl = *(const short8_t*)(POl + oo);
        }
        boh[i] = zh; bol[i] = zl;
    }

    // combine identity: all 512 threads, b = tid>>3, jj = tid&7
    const int cb = tid >> 3, cjj = tid & 7;
    float c_reg = c0[(size_t)cb * 1024 + 8 * ng + cjj];
    ushort4_t xq = *(const ushort4_t*)(xpf + ((size_t)ng * 64 + cb) * 32 + cjj * 4);

    // h-store address pieces: j-range [8ng,8ng+8) = one full 8-elem group
    const int ks2  = ng >> 2;
    const int l2hi = (ng & 3) << 4;

#pragma unroll 1
    for (int t = 0; t <= T_STEPS; ++t) {
        const unsigned short* hc = (t & 1) ? hB : hA;
        unsigned short*       hn = (t & 1) ? hA : hB;

        f32x4 acc[4][3];
#pragma unroll
        for (int mt = 0; mt < 4; ++mt)
#pragma unroll
            for (int nc = 0; nc < 3; ++nc)
                acc[mt][nc] = (f32x4){0.f, 0.f, 0.f, 0.f};

#pragma unroll
        for (int i = 0; i < 4; ++i) {
            const int ks = 4 * kq + i;
            short8_t ah[4], al[4];
#pragma unroll
            for (int mt = 0; mt < 4; ++mt) {
                int off = ((mt * 32 + ks) * 64 + lane) * 8;
                union { short8_t v; unsigned long long q[2]; } uh, ul;
                const unsigned long long* ph = (const unsigned long long*)(hc + off);
                const unsigned long long* pl = (const unsigned long long*)(hc + 65536 + off);
                uh.q[0] = __hip_atomic_load(ph,     __ATOMIC_RELAXED, __HIP_MEMORY_SCOPE_SYSTEM);
                uh.q[1] = __hip_atomic_load(ph + 1, __ATOMIC_RELAXED, __HIP_MEMORY_SCOPE_SYSTEM);
                ul.q[0] = __hip_atomic_load(pl,     __ATOMIC_RELAXED, __HIP_MEMORY_SCOPE_SYSTEM);
                ul.q[1] = __hip_atomic_load(pl + 1, __ATOMIC_RELAXED, __HIP_MEMORY_SCOPE_SYSTEM);
                ah[mt] = uh.v;
                al[mt] = ul.v;
            }
#pragma unroll
            for (int mt = 0; mt < 4; ++mt) {
                acc[mt][0] = __builtin_amdgcn_mfma_f32_16x16x32_bf16(ah[mt], bgh[0][i], acc[mt][0], 0,0,0);
                acc[mt][1] = __builtin_amdgcn_mfma_f32_16x16x32_bf16(ah[mt], bgh[1][i], acc[mt][1], 0,0,0);
                acc[mt][2] = __builtin_amdgcn_mfma_f32_16x16x32_bf16(ah[mt], boh[i],    acc[mt][2], 0,0,0);
                acc[mt][0] = __builtin_amdgcn_mfma_f32_16x16x32_bf16(al[mt], bgh[0][i], acc[mt][0], 0,0,0);
                acc[mt][1] = __builtin_amdgcn_mfma_f32_16x16x32_bf16(al[mt], bgh[1][i], acc[mt][1], 0,0,0);
                acc[mt][2] = __builtin_amdgcn_mfma_f32_16x16x32_bf16(al[mt], boh[i],    acc[mt][2], 0,0,0);
                acc[mt][0] = __builtin_amdgcn_mfma_f32_16x16x32_bf16(ah[mt], bgl[0][i], acc[mt][0], 0,0,0);
                acc[mt][1] = __builtin_amdgcn_mfma_f32_16x16x32_bf16(ah[mt], bgl[1][i], acc[mt][1], 0,0,0);
                acc[mt][2] = __builtin_amdgcn_mfma_f32_16x16x32_bf16(ah[mt], bol[i],    acc[mt][2], 0,0,0);
            }
        }

        // ---- K-reduction across 8 waves (12 tiles) ----
#pragma unroll
        for (int mt = 0; mt < 4; ++mt)
#pragma unroll
            for (int nc = 0; nc < 3; ++nc)
                red[kq][mt * 3 + nc][lane] = acc[mt][nc];
        __syncthreads();
        {
            f32x4 s = red[0][kq][lane];
#pragma unroll
            for (int q = 1; q < 8; ++q) s += red[q][kq][lane];
            redF[kq][lane] = s;
        }
        if (kq < 4) {
            const int tl = 8 + kq;
            f32x4 s = red[0][tl][lane];
#pragma unroll
            for (int q = 1; q < 8; ++q) s += red[q][tl][lane];
            redF[tl][lane] = s;
        }
        __syncthreads();

        // ---- combine (all 512 threads): gates -> c,h ; out[t-1] ----
        {
            const int mt = cb >> 4;
            const int lnb = (cb & 12) << 2;
            const int rg = cb & 3;
            float ov = redF[mt * 3 + 2][lnb | cjj][rg];
            if (t > 0)
                out[(size_t)(t - 1) * 65536 + cb * 1024 + 8 * ng + cjj] = ov;
            if (t < T_STEPS) {
                const int nt = cjj >> 2;
                float pre0 = redF[mt * 3 + nt][lnb | (0  + (cjj & 3))][rg] + bf2f(xq[0]);
                float pre1 = redF[mt * 3 + nt][lnb | (4  + (cjj & 3))][rg] + bf2f(xq[1]);
                float pre2 = redF[mt * 3 + nt][lnb | (8  + (cjj & 3))][rg] + bf2f(xq[2]);
                float pre3 = redF[mt * 3 + nt][lnb | (12 + (cjj & 3))][rg] + bf2f(xq[3]);
                float gi = 1.f / (1.f + expf(-pre0));
                float gf = 1.f / (1.f + expf(-pre1));
                float go = 1.f / (1.f + expf(-pre2));
                float cn = gf * c_reg + gi * tanhf(pre3);
                c_reg = cn;
                float hv = go * tanhf(cn);
                unsigned short hhi = f2bf(hv);
                unsigned short hlo = f2bf(hv - bf2f(hhi));
                hsc[(cb * 2 + 0) * 8 + cjj] = hhi;
                hsc[(cb * 2 + 1) * 8 + cjj] = hlo;
                if (t + 1 < T_STEPS)
                    xq = *(const ushort4_t*)(xpf +
                        (((size_t)(t + 1) * NBLK + ng) * 64 + cb) * 32 + cjj * 4);
            }
        }
        __syncthreads();

        // ---- h (bf16 hi/lo) 16B-per-thread bypass stores ----
        if (tid < 128 && t < T_STEPS) {
            int b = tid >> 1, cp = tid & 1;
            union { short8_t v; unsigned long long q[2]; } u;
            u.v = *(const short8_t*)&hsc[(b * 2 + cp) * 8];
            int elem = (((cp * 4 + (b >> 4)) * 32 + ks2) * 64 + ((b & 15) | l2hi)) * 8;
            __hip_atomic_store((unsigned long long*)(hn + elem),     u.q[0],
                               __ATOMIC_RELAXED, __HIP_MEMORY_SCOPE_SYSTEM);
            __hip_atomic_store((unsigned long long*)(hn + elem + 4), u.q[1],
                               __ATOMIC_RELAXED, __HIP_MEMORY_SCOPE_SYSTEM);
        }

        // ---- striped grid barrier: relaxed SYSTEM, no cache invalidates ----
        if (t < T_STEPS) {
            __syncthreads();
            if (tid == 0) {
                asm volatile("s_waitcnt vmcnt(0)" ::: "memory");
                const unsigned tgt = (unsigned)(t + 1);
                unsigned* scnt = bar + (ng >> 3) * 32;            // 16 stripes
                unsigned old = __hip_atomic_fetch_add(scnt, 1u,
                                   __ATOMIC_RELAXED, __HIP_MEMORY_SCOPE_SYSTEM);
                if (old == 8u * tgt - 1u) {
                    unsigned om = __hip_atomic_fetch_add(bar + 512, 1u,
                                   __ATOMIC_RELAXED, __HIP_MEMORY_SCOPE_SYSTEM);
                    if (om == 16u * tgt - 1u) {
#pragma unroll
                        for (int f = 0; f < 16; ++f)
                            __hip_atomic_store(bar + 576 + f * 32, tgt,
                                   __ATOMIC_RELAXED, __HIP_MEMORY_SCOPE_SYSTEM);
                    }
                }
                while (__hip_atomic_load(bar + 576 + (ng & 15) * 32,
                           __ATOMIC_RELAXED, __HIP_MEMORY_SCOPE_SYSTEM) < tgt)
                    __builtin_amdgcn_s_sleep(2);
            }
            __syncthreads();
        }
    }
}

// ---------------------------------------------------------------------------
extern "C" void kernel_launch(void* const* d_in, const int* in_sizes, int n_in,
                              void* d_out, int out_size, void* d_ws, size_t ws_size,
                              hipStream_t stream)
{
    const float* x    = (const float*)d_in[0];
    const float* h0   = (const float*)d_in[1];
    const float* c0   = (const float*)d_in[2];
    const float* Wxi  = (const float*)d_in[3];
    const float* Wxf  = (const float*)d_in[4];
    const float* Wxo  = (const float*)d_in[5];
    const float* Wxc  = (const float*)d_in[6];
    const float* Whi  = (const float*)d_in[7];
    const float* Whf  = (const float*)d_in[8];
    const float* Who  = (const float*)d_in[9];
    const float* Whc  = (const float*)d_in[10];
    const float* Wout = (const float*)d_in[11];
    float* out = (float*)d_out;

    const size_t PG_B  = (size_t)NBLK * 2 * 32 * 64 * 8 * 2;   //  8,388,608 each
    const size_t PO_B  = (size_t)NBLK * 32 * 32 * 8 * 2;       //  2,097,152 each
    const size_t HF_B  = (size_t)2 * 4 * 32 * 64 * 8 * 2;      //    262,144 each
    const size_t BAR_B = 8192;
    const size_t XPF_B = (size_t)T_STEPS * NBLK * 64 * 32 * 2; // 134,217,728

    char* ws = (char*)d_ws;
    unsigned short* PGh = (unsigned short*)ws;  ws += PG_B;
    unsigned short* PGl = (unsigned short*)ws;  ws += PG_B;
    unsigned short* POh = (unsigned short*)ws;  ws += PO_B;
    unsigned short* POl = (unsigned short*)ws;  ws += PO_B;
    unsigned short* hA  = (unsigned short*)ws;  ws += HF_B;
    unsigned short* hB  = (unsigned short*)ws;  ws += HF_B;
    unsigned*       bar = (unsigned*)ws;        ws += BAR_B;
    unsigned short* xpf = (unsigned short*)ws;  ws += XPF_B;

    hipMemsetAsync(bar, 0, BAR_B, stream);
    pack_gate<<<dim3(16, NBLK), 256, 0, stream>>>(Whi, Whf, Who, Whc, PGh, PGl);
    pack_out<<<dim3(4, NBLK), 256, 0, stream>>>(Wout, POh, POl);
    trans_h0f<<<dim3(64), 256, 0, stream>>>(h0, hA);
    xproj_mfma<<<dim3(128, 32), 256, 0, stream>>>(x, Wxi, Wxf, Wxo, Wxc, xpf);

    lstm_loop6<<<dim3(NBLK), dim3(512), 0, stream>>>(
        xpf, PGh, PGl, POh, POl, c0, hA, hB, out, bar);
}

// Round 12
// 3577.287 us; speedup vs baseline: 1.0574x; 1.0074x over previous
//
#include <hip/hip_runtime.h>
#include <hip/hip_bf16.h>
#include <math.h>

#define T_STEPS 256
#define NBLK    128

typedef __attribute__((ext_vector_type(8))) short short8_t;   // 8 bf16
typedef __attribute__((ext_vector_type(4))) float f32x4;
typedef __attribute__((ext_vector_type(4))) unsigned short ushort4_t;

__device__ __forceinline__ unsigned short f2bf(float v) {
    __hip_bfloat16 h = __float2bfloat16(v);
    return *reinterpret_cast<unsigned short*>(&h);
}
__device__ __forceinline__ float bf2f(unsigned short u) {
    __hip_bfloat16 h;
    *reinterpret_cast<unsigned short*>(&h) = u;
    return __bfloat162float(h);
}

// ---------------------------------------------------------------------------
// pack_gate: gate-weight B-fragments for 128-block layout, bf16 hi/lo.
// Block ng owns j in [8ng, 8ng+8): 2 n-tiles (nt). Within tile nt, col
// n = lane&15 -> g = n>>2, j = 8ng + nt*4 + (n&3); k = ks*32+(lane>>4)*8+e.
// ---------------------------------------------------------------------------
__global__ __launch_bounds__(256) void pack_gate(
    const float* __restrict__ Wi, const float* __restrict__ Wf,
    const float* __restrict__ Wo, const float* __restrict__ Wc,
    unsigned short* __restrict__ PGh, unsigned short* __restrict__ PGl)
{
    int ng = blockIdx.y;
    int slot = blockIdx.x * 4 + (threadIdx.x >> 6);   // 0..63
    int nt = slot >> 5, ks = slot & 31;
    int lane = threadIdx.x & 63;
    int n = lane & 15, g = n >> 2;
    int j = 8 * ng + nt * 4 + (n & 3);
    int k0 = ks * 32 + (lane >> 4) * 8;
    const float* W = (g == 0) ? Wi : (g == 1) ? Wf : (g == 2) ? Wo : Wc;
    const float* src = W + (size_t)j * 1024 + k0;

    union { short8_t v; unsigned short u[8]; } hi, lo;
#pragma unroll
    for (int e = 0; e < 8; ++e) {
        float v = src[e];
        hi.u[e] = f2bf(v);
        lo.u[e] = f2bf(v - bf2f(hi.u[e]));
    }
    size_t o = (((size_t)(ng * 2 + nt) * 32 + ks) * 64 + lane) * 8;
    *(short8_t*)(PGh + o) = hi.v;
    *(short8_t*)(PGl + o) = lo.v;
}

// ---------------------------------------------------------------------------
// pack_out: compact out-weight frags (8 real cols per block).
// dst[((ng*32+ks)*32 + kb*8 + n)*8 + e] = Wout[8ng+n][ks*32+kb*8+e]
// ---------------------------------------------------------------------------
__global__ __launch_bounds__(256) void pack_out(
    const float* __restrict__ Wout,
    unsigned short* __restrict__ POh, unsigned short* __restrict__ POl)
{
    int ng = blockIdx.y;
    int ks = blockIdx.x * 8 + (threadIdx.x >> 5);
    int sl = threadIdx.x & 31;
    int kb = sl >> 3, n = sl & 7;
    int j = 8 * ng + n;
    int k0 = ks * 32 + kb * 8;
    const float* src = Wout + (size_t)j * 1024 + k0;

    union { short8_t v; unsigned short u[8]; } hi, lo;
#pragma unroll
    for (int e = 0; e < 8; ++e) {
        float v = src[e];
        hi.u[e] = f2bf(v);
        lo.u[e] = f2bf(v - bf2f(hi.u[e]));
    }
    size_t o = (((size_t)ng * 32 + ks) * 32 + sl) * 8;
    *(short8_t*)(POh + o) = hi.v;
    *(short8_t*)(POl + o) = lo.v;
}

// ---------------------------------------------------------------------------
// trans_h0f: h0[b][k] -> A-fragment layout [copy][mt][ks][lane][8] bf16 hi/lo
// ---------------------------------------------------------------------------
__global__ __launch_bounds__(256) void trans_h0f(
    const float* __restrict__ h0, unsigned short* __restrict__ hA)
{
    int id = blockIdx.x * 256 + threadIdx.x;   // [0, 16384)
    int lane = id & 63;
    int ks = (id >> 6) & 31;
    int mt = (id >> 11) & 3;
    int copy = id >> 13;
    int b = mt * 16 + (lane & 15);
    int k = ks * 32 + (lane >> 4) * 8;
    const float* src = h0 + (size_t)b * 1024 + k;

    union { short8_t v; unsigned short u[8]; } o;
#pragma unroll
    for (int e = 0; e < 8; ++e) {
        float v = src[e];
        unsigned short hb = f2bf(v);
        o.u[e] = (copy == 0) ? hb : f2bf(v - bf2f(hb));
    }
    *(short8_t*)(hA + (size_t)id * 8) = o.v;
}

// ---------------------------------------------------------------------------
// xproj bf16 MFMA GEMM; epilogue scatters to xpf[t][ng(128)][b][jj(8)][g(4)].
// ---------------------------------------------------------------------------
__global__ __launch_bounds__(256) void xproj_mfma(
    const float* __restrict__ X,
    const float* __restrict__ W0, const float* __restrict__ W1,
    const float* __restrict__ W2, const float* __restrict__ W3,
    unsigned short* __restrict__ xpf)
{
    __shared__ short8_t As[4 * 128];
    __shared__ short8_t Bs[4 * 128];

    const int bm = blockIdx.x;
    const int bn = blockIdx.y;
    const float* W = (bn < 8) ? W0 : (bn < 16) ? W1 : (bn < 24) ? W2 : W3;
    const int jbase = (bn & 7) * 128;
    const int m0 = bm * 128;

    const int tid  = threadIdx.x;
    const int lane = tid & 63;
    const int wave = tid >> 6;
    const int wm = wave >> 1, wn = wave & 1;
    const int q  = lane >> 4;
    const int lr = lane & 15;

    f32x4 acc[4][4];
#pragma unroll
    for (int i = 0; i < 4; ++i)
#pragma unroll
        for (int j = 0; j < 4; ++j) acc[i][j] = (f32x4){0.f, 0.f, 0.f, 0.f};

    for (int k0 = 0; k0 < 1024; k0 += 32) {
#pragma unroll
        for (int ss = 0; ss < 2; ++ss) {
            int s  = tid + ss * 256;
            int kg = s & 3, r = s >> 2;
            const float* xa = X + (size_t)(m0 + r) * 1024 + k0 + kg * 8;
            const float* wb = W + (size_t)(jbase + r) * 1024 + k0 + kg * 8;
            float4 a0 = *(const float4*)(xa);
            float4 a1 = *(const float4*)(xa + 4);
            float4 b0 = *(const float4*)(wb);
            float4 b1 = *(const float4*)(wb + 4);
            union { short8_t v; unsigned short u[8]; } ua, ub;
            float af[8] = {a0.x,a0.y,a0.z,a0.w,a1.x,a1.y,a1.z,a1.w};
            float bf[8] = {b0.x,b0.y,b0.z,b0.w,b1.x,b1.y,b1.z,b1.w};
#pragma unroll
            for (int e = 0; e < 8; ++e) {
                ua.u[e] = f2bf(af[e]);
                ub.u[e] = f2bf(bf[e]);
            }
            As[kg * 128 + r] = ua.v;
            Bs[kg * 128 + r] = ub.v;
        }
        __syncthreads();

        short8_t a[4], b[4];
#pragma unroll
        for (int mi = 0; mi < 4; ++mi)
            a[mi] = As[q * 128 + wm * 64 + mi * 16 + lr];
#pragma unroll
        for (int nj = 0; nj < 4; ++nj)
            b[nj] = Bs[q * 128 + wn * 64 + nj * 16 + lr];
#pragma unroll
        for (int mi = 0; mi < 4; ++mi)
#pragma unroll
            for (int nj = 0; nj < 4; ++nj)
                acc[mi][nj] = __builtin_amdgcn_mfma_f32_16x16x32_bf16(
                    a[mi], b[nj], acc[mi][nj], 0, 0, 0);
        __syncthreads();
    }

#pragma unroll
    for (int mi = 0; mi < 4; ++mi)
#pragma unroll
        for (int nj = 0; nj < 4; ++nj)
#pragma unroll
            for (int r = 0; r < 4; ++r) {
                int m = m0 + wm * 64 + mi * 16 + q * 4 + r;
                int n = bn * 128 + wn * 64 + nj * 16 + lr;
                int tt = m >> 6, bb = m & 63;
                int g = n >> 10, jc = n & 1023;
                xpf[(((size_t)tt * NBLK + (jc >> 3)) * 64 + bb) * 32 + (jc & 7) * 4 + g]
                    = f2bf(acc[mi][nj][r]);
            }
}

// ---------------------------------------------------------------------------
// Persistent MFMA LSTM loop, 128 blocks, striped relaxed-SYSTEM barrier.
// Round-12 change: combine threads publish h directly (shfl pair-pack ->
// 4B system-scope stores), removing the hsc LDS bounce and one syncthreads.
// ---------------------------------------------------------------------------
__global__ __launch_bounds__(512, 1) void lstm_loop10(
    const unsigned short* __restrict__ xpf,
    const unsigned short* __restrict__ PGh, const unsigned short* __restrict__ PGl,
    const unsigned short* __restrict__ POh, const unsigned short* __restrict__ POl,
    const float* __restrict__ c0,
    unsigned short* __restrict__ hA, unsigned short* __restrict__ hB,
    float* __restrict__ out,
    unsigned* __restrict__ bar)
{
    __shared__ f32x4 red[8][12][64];    // [wave][mt*3+nc][lane]  96 KB
    __shared__ f32x4 redF[12][64];      //                        12 KB

    const int tid  = threadIdx.x;
    const int lane = tid & 63;
    const int kq   = tid >> 6;
    const int ng   = blockIdx.x;        // 0..127

    // ---- persistent B fragments in registers ----
    short8_t bgh[2][4], bgl[2][4], boh[4], bol[4];
#pragma unroll
    for (int i = 0; i < 4; ++i) {
        int ks = 4 * kq + i;
#pragma unroll
        for (int nt = 0; nt < 2; ++nt) {
            size_t og = (((size_t)(ng * 2 + nt) * 32 + ks) * 64 + lane) * 8;
            bgh[nt][i] = *(const short8_t*)(PGh + og);
            bgl[nt][i] = *(const short8_t*)(PGl + og);
        }
        short8_t zh = {0,0,0,0,0,0,0,0};
        short8_t zl = {0,0,0,0,0,0,0,0};
        if ((lane & 15) < 8) {
            size_t oo = (((size_t)ng * 32 + ks) * 32 + (lane >> 4) * 8 + (lane & 7)) * 8;
            zh = *(const short8_t*)(POh + oo);
            zl = *(const short8_t*)(POl + oo);
        }
        boh[i] = zh; bol[i] = zl;
    }

    // combine identity: all 512 threads, b = tid>>3, jj = tid&7
    const int cb = tid >> 3, cjj = tid & 7;
    float c_reg = c0[(size_t)cb * 1024 + 8 * ng + cjj];
    ushort4_t xq = *(const ushort4_t*)(xpf + ((size_t)ng * 64 + cb) * 32 + cjj * 4);

    // h-store address pieces: j-range [8ng,8ng+8) = one full 8-elem k-group
    const int ks2  = ng >> 2;
    const int l2hi = (ng & 3) << 4;
    // short index of this combine-thread's hi-half h slot (j = 8ng+cjj):
    const unsigned hbase = ((((unsigned)(cb >> 4)) * 32 + ks2) * 64 + ((cb & 15) | l2hi)) * 8 + cjj;

#pragma unroll 1
    for (int t = 0; t <= T_STEPS; ++t) {
        const unsigned short* hc = (t & 1) ? hB : hA;
        unsigned short*       hn = (t & 1) ? hA : hB;

        f32x4 acc[4][3];
#pragma unroll
        for (int mt = 0; mt < 4; ++mt)
#pragma unroll
            for (int nc = 0; nc < 3; ++nc)
                acc[mt][nc] = (f32x4){0.f, 0.f, 0.f, 0.f};

#pragma unroll
        for (int i = 0; i < 4; ++i) {
            const int ks = 4 * kq + i;
            short8_t ah[4], al[4];
#pragma unroll
            for (int mt = 0; mt < 4; ++mt) {
                int off = ((mt * 32 + ks) * 64 + lane) * 8;
                union { short8_t v; unsigned long long q[2]; } uh, ul;
                const unsigned long long* ph = (const unsigned long long*)(hc + off);
                const unsigned long long* pl = (const unsigned long long*)(hc + 65536 + off);
                uh.q[0] = __hip_atomic_load(ph,     __ATOMIC_RELAXED, __HIP_MEMORY_SCOPE_SYSTEM);
                uh.q[1] = __hip_atomic_load(ph + 1, __ATOMIC_RELAXED, __HIP_MEMORY_SCOPE_SYSTEM);
                ul.q[0] = __hip_atomic_load(pl,     __ATOMIC_RELAXED, __HIP_MEMORY_SCOPE_SYSTEM);
                ul.q[1] = __hip_atomic_load(pl + 1, __ATOMIC_RELAXED, __HIP_MEMORY_SCOPE_SYSTEM);
                ah[mt] = uh.v;
                al[mt] = ul.v;
            }
#pragma unroll
            for (int mt = 0; mt < 4; ++mt) {
                acc[mt][0] = __builtin_amdgcn_mfma_f32_16x16x32_bf16(ah[mt], bgh[0][i], acc[mt][0], 0,0,0);
                acc[mt][1] = __builtin_amdgcn_mfma_f32_16x16x32_bf16(ah[mt], bgh[1][i], acc[mt][1], 0,0,0);
                acc[mt][2] = __builtin_amdgcn_mfma_f32_16x16x32_bf16(ah[mt], boh[i],    acc[mt][2], 0,0,0);
                acc[mt][0] = __builtin_amdgcn_mfma_f32_16x16x32_bf16(al[mt], bgh[0][i], acc[mt][0], 0,0,0);
                acc[mt][1] = __builtin_amdgcn_mfma_f32_16x16x32_bf16(al[mt], bgh[1][i], acc[mt][1], 0,0,0);
                acc[mt][2] = __builtin_amdgcn_mfma_f32_16x16x32_bf16(al[mt], boh[i],    acc[mt][2], 0,0,0);
                acc[mt][0] = __builtin_amdgcn_mfma_f32_16x16x32_bf16(ah[mt], bgl[0][i], acc[mt][0], 0,0,0);
                acc[mt][1] = __builtin_amdgcn_mfma_f32_16x16x32_bf16(ah[mt], bgl[1][i], acc[mt][1], 0,0,0);
                acc[mt][2] = __builtin_amdgcn_mfma_f32_16x16x32_bf16(ah[mt], bol[i],    acc[mt][2], 0,0,0);
            }
        }

        // ---- K-reduction across 8 waves (12 tiles) ----
#pragma unroll
        for (int mt = 0; mt < 4; ++mt)
#pragma unroll
            for (int nc = 0; nc < 3; ++nc)
                red[kq][mt * 3 + nc][lane] = acc[mt][nc];
        __syncthreads();
        {
            f32x4 s = red[0][kq][lane];
#pragma unroll
            for (int q = 1; q < 8; ++q) s += red[q][kq][lane];
            redF[kq][lane] = s;
        }
        if (kq < 4) {
            const int tl = 8 + kq;
            f32x4 s = red[0][tl][lane];
#pragma unroll
            for (int q = 1; q < 8; ++q) s += red[q][tl][lane];
            redF[tl][lane] = s;
        }
        __syncthreads();

        // ---- combine (all 512 threads): gates -> c,h (direct publish) ; out ----
        {
            const int mt = cb >> 4;
            const int lnb = (cb & 12) << 2;
            const int rg = cb & 3;
            float ov = redF[mt * 3 + 2][lnb | cjj][rg];
            if (t > 0)
                out[(size_t)(t - 1) * 65536 + cb * 1024 + 8 * ng + cjj] = ov;
            if (t < T_STEPS) {
                const int nt = cjj >> 2;
                float pre0 = redF[mt * 3 + nt][lnb | (0  + (cjj & 3))][rg] + bf2f(xq[0]);
                float pre1 = redF[mt * 3 + nt][lnb | (4  + (cjj & 3))][rg] + bf2f(xq[1]);
                float pre2 = redF[mt * 3 + nt][lnb | (8  + (cjj & 3))][rg] + bf2f(xq[2]);
                float pre3 = redF[mt * 3 + nt][lnb | (12 + (cjj & 3))][rg] + bf2f(xq[3]);
                float gi = 1.f / (1.f + expf(-pre0));
                float gf = 1.f / (1.f + expf(-pre1));
                float go = 1.f / (1.f + expf(-pre2));
                float cn = gf * c_reg + gi * tanhf(pre3);
                c_reg = cn;
                float hv = go * tanhf(cn);
                unsigned short hhi = f2bf(hv);
                unsigned short hlo = f2bf(hv - bf2f(hhi));

                // pair-pack with neighbor lane (cjj+1) and publish directly
                unsigned hhiN = (unsigned short)__shfl_down((int)hhi, 1);
                unsigned hloN = (unsigned short)__shfl_down((int)hlo, 1);
                if ((cjj & 1) == 0) {
                    unsigned hp = (unsigned)hhi | (hhiN << 16);
                    unsigned lp = (unsigned)hlo | (hloN << 16);
                    __hip_atomic_store((unsigned*)(hn + hbase), hp,
                                       __ATOMIC_RELAXED, __HIP_MEMORY_SCOPE_SYSTEM);
                    __hip_atomic_store((unsigned*)(hn + hbase + 65536), lp,
                                       __ATOMIC_RELAXED, __HIP_MEMORY_SCOPE_SYSTEM);
                }
                if (t + 1 < T_STEPS)
                    xq = *(const ushort4_t*)(xpf +
                        (((size_t)(t + 1) * NBLK + ng) * 64 + cb) * 32 + cjj * 4);
            }
        }

        // ---- striped grid barrier: relaxed SYSTEM, no cache invalidates ----
        if (t < T_STEPS) {
            __syncthreads();   // drains every wave's h stores (compiler vmcnt0)
            if (tid == 0) {
                const unsigned tgt = (unsigned)(t + 1);
                unsigned* scnt = bar + (ng >> 3) * 32;            // 16 stripes
                unsigned old = __hip_atomic_fetch_add(scnt, 1u,
                                   __ATOMIC_RELAXED, __HIP_MEMORY_SCOPE_SYSTEM);
                if (old == 8u * tgt - 1u) {
                    unsigned om = __hip_atomic_fetch_add(bar + 512, 1u,
                                   __ATOMIC_RELAXED, __HIP_MEMORY_SCOPE_SYSTEM);
                    if (om == 16u * tgt - 1u) {
#pragma unroll
                        for (int f = 0; f < 16; ++f)
                            __hip_atomic_store(bar + 576 + f * 32, tgt,
                                   __ATOMIC_RELAXED, __HIP_MEMORY_SCOPE_SYSTEM);
                    }
                }
                while (__hip_atomic_load(bar + 576 + (ng & 15) * 32,
                           __ATOMIC_RELAXED, __HIP_MEMORY_SCOPE_SYSTEM) < tgt)
                    __builtin_amdgcn_s_sleep(2);
            }
            __syncthreads();
        }
    }
}

// ---------------------------------------------------------------------------
extern "C" void kernel_launch(void* const* d_in, const int* in_sizes, int n_in,
                              void* d_out, int out_size, void* d_ws, size_t ws_size,
                              hipStream_t stream)
{
    const float* x    = (const float*)d_in[0];
    const float* h0   = (const float*)d_in[1];
    const float* c0   = (const float*)d_in[2];
    const float* Wxi  = (const float*)d_in[3];
    const float* Wxf  = (const float*)d_in[4];
    const float* Wxo  = (const float*)d_in[5];
    const float* Wxc  = (const float*)d_in[6];
    const float* Whi  = (const float*)d_in[7];
    const float* Whf  = (const float*)d_in[8];
    const float* Who  = (const float*)d_in[9];
    const float* Whc  = (const float*)d_in[10];
    const float* Wout = (const float*)d_in[11];
    float* out = (float*)d_out;

    const size_t PG_B  = (size_t)NBLK * 2 * 32 * 64 * 8 * 2;   //  8,388,608 each
    const size_t PO_B  = (size_t)NBLK * 32 * 32 * 8 * 2;       //  2,097,152 each
    const size_t HF_B  = (size_t)2 * 4 * 32 * 64 * 8 * 2;      //    262,144 each
    const size_t BAR_B = 8192;
    const size_t XPF_B = (size_t)T_STEPS * NBLK * 64 * 32 * 2; // 134,217,728

    char* ws = (char*)d_ws;
    unsigned short* PGh = (unsigned short*)ws;  ws += PG_B;
    unsigned short* PGl = (unsigned short*)ws;  ws += PG_B;
    unsigned short* POh = (unsigned short*)ws;  ws += PO_B;
    unsigned short* POl = (unsigned short*)ws;  ws += PO_B;
    unsigned short* hA  = (unsigned short*)ws;  ws += HF_B;
    unsigned short* hB  = (unsigned short*)ws;  ws += HF_B;
    unsigned*       bar = (unsigned*)ws;        ws += BAR_B;
    unsigned short* xpf = (unsigned short*)ws;  ws += XPF_B;

    hipMemsetAsync(bar, 0, BAR_B, stream);
    pack_gate<<<dim3(16, NBLK), 256, 0, stream>>>(Whi, Whf, Who, Whc, PGh, PGl);
    pack_out<<<dim3(4, NBLK), 256, 0, stream>>>(Wout, POh, POl);
    trans_h0f<<<dim3(64), 256, 0, stream>>>(h0, hA);
    xproj_mfma<<<dim3(128, 32), 256, 0, stream>>>(x, Wxi, Wxf, Wxo, Wxc, xpf);

    lstm_loop10<<<dim3(NBLK), dim3(512), 0, stream>>>(
        xpf, PGh, PGl, POh, POl, c0, hA, hB, out, bar);
}

// Round 13
// 2572.050 us; speedup vs baseline: 1.4706x; 1.3908x over previous
//
#include <hip/hip_runtime.h>
#include <hip/hip_bf16.h>
#include <math.h>

#define T_STEPS 256
#define NBLK    128

typedef __attribute__((ext_vector_type(8))) short short8_t;   // 8 bf16
typedef __attribute__((ext_vector_type(4))) float f32x4;
typedef __attribute__((ext_vector_type(4))) unsigned short ushort4_t;

__device__ __forceinline__ unsigned short f2bf(float v) {
    __hip_bfloat16 h = __float2bfloat16(v);
    return *reinterpret_cast<unsigned short*>(&h);
}
__device__ __forceinline__ float bf2f(unsigned short u) {
    __hip_bfloat16 h;
    *reinterpret_cast<unsigned short*>(&h) = u;
    return __bfloat162float(h);
}

// ---------------------------------------------------------------------------
// pack_gate: gate-weight B-fragments for 128-block layout, bf16 hi/lo.
// ---------------------------------------------------------------------------
__global__ __launch_bounds__(256) void pack_gate(
    const float* __restrict__ Wi, const float* __restrict__ Wf,
    const float* __restrict__ Wo, const float* __restrict__ Wc,
    unsigned short* __restrict__ PGh, unsigned short* __restrict__ PGl)
{
    int ng = blockIdx.y;
    int slot = blockIdx.x * 4 + (threadIdx.x >> 6);   // 0..63
    int nt = slot >> 5, ks = slot & 31;
    int lane = threadIdx.x & 63;
    int n = lane & 15, g = n >> 2;
    int j = 8 * ng + nt * 4 + (n & 3);
    int k0 = ks * 32 + (lane >> 4) * 8;
    const float* W = (g == 0) ? Wi : (g == 1) ? Wf : (g == 2) ? Wo : Wc;
    const float* src = W + (size_t)j * 1024 + k0;

    union { short8_t v; unsigned short u[8]; } hi, lo;
#pragma unroll
    for (int e = 0; e < 8; ++e) {
        float v = src[e];
        hi.u[e] = f2bf(v);
        lo.u[e] = f2bf(v - bf2f(hi.u[e]));
    }
    size_t o = (((size_t)(ng * 2 + nt) * 32 + ks) * 64 + lane) * 8;
    *(short8_t*)(PGh + o) = hi.v;
    *(short8_t*)(PGl + o) = lo.v;
}

// ---------------------------------------------------------------------------
// pack_out: compact out-weight frags (8 real cols per block).
// ---------------------------------------------------------------------------
__global__ __launch_bounds__(256) void pack_out(
    const float* __restrict__ Wout,
    unsigned short* __restrict__ POh, unsigned short* __restrict__ POl)
{
    int ng = blockIdx.y;
    int ks = blockIdx.x * 8 + (threadIdx.x >> 5);
    int sl = threadIdx.x & 31;
    int kb = sl >> 3, n = sl & 7;
    int j = 8 * ng + n;
    int k0 = ks * 32 + kb * 8;
    const float* src = Wout + (size_t)j * 1024 + k0;

    union { short8_t v; unsigned short u[8]; } hi, lo;
#pragma unroll
    for (int e = 0; e < 8; ++e) {
        float v = src[e];
        hi.u[e] = f2bf(v);
        lo.u[e] = f2bf(v - bf2f(hi.u[e]));
    }
    size_t o = (((size_t)ng * 32 + ks) * 32 + sl) * 8;
    *(short8_t*)(POh + o) = hi.v;
    *(short8_t*)(POl + o) = lo.v;
}

// ---------------------------------------------------------------------------
// trans_h0f: h0[b][k] -> A-fragment layout [copy][mt][ks][lane][8] bf16 hi/lo
// ---------------------------------------------------------------------------
__global__ __launch_bounds__(256) void trans_h0f(
    const float* __restrict__ h0, unsigned short* __restrict__ hA)
{
    int id = blockIdx.x * 256 + threadIdx.x;   // [0, 16384)
    int lane = id & 63;
    int ks = (id >> 6) & 31;
    int mt = (id >> 11) & 3;
    int copy = id >> 13;
    int b = mt * 16 + (lane & 15);
    int k = ks * 32 + (lane >> 4) * 8;
    const float* src = h0 + (size_t)b * 1024 + k;

    union { short8_t v; unsigned short u[8]; } o;
#pragma unroll
    for (int e = 0; e < 8; ++e) {
        float v = src[e];
        unsigned short hb = f2bf(v);
        o.u[e] = (copy == 0) ? hb : f2bf(v - bf2f(hb));
    }
    *(short8_t*)(hA + (size_t)id * 8) = o.v;
}

// ---------------------------------------------------------------------------
// xproj bf16 MFMA GEMM; epilogue scatters to xpf[t][ng(128)][b][jj(8)][g(4)].
// ---------------------------------------------------------------------------
__global__ __launch_bounds__(256) void xproj_mfma(
    const float* __restrict__ X,
    const float* __restrict__ W0, const float* __restrict__ W1,
    const float* __restrict__ W2, const float* __restrict__ W3,
    unsigned short* __restrict__ xpf)
{
    __shared__ short8_t As[4 * 128];
    __shared__ short8_t Bs[4 * 128];

    const int bm = blockIdx.x;
    const int bn = blockIdx.y;
    const float* W = (bn < 8) ? W0 : (bn < 16) ? W1 : (bn < 24) ? W2 : W3;
    const int jbase = (bn & 7) * 128;
    const int m0 = bm * 128;

    const int tid  = threadIdx.x;
    const int lane = tid & 63;
    const int wave = tid >> 6;
    const int wm = wave >> 1, wn = wave & 1;
    const int q  = lane >> 4;
    const int lr = lane & 15;

    f32x4 acc[4][4];
#pragma unroll
    for (int i = 0; i < 4; ++i)
#pragma unroll
        for (int j = 0; j < 4; ++j) acc[i][j] = (f32x4){0.f, 0.f, 0.f, 0.f};

    for (int k0 = 0; k0 < 1024; k0 += 32) {
#pragma unroll
        for (int ss = 0; ss < 2; ++ss) {
            int s  = tid + ss * 256;
            int kg = s & 3, r = s >> 2;
            const float* xa = X + (size_t)(m0 + r) * 1024 + k0 + kg * 8;
            const float* wb = W + (size_t)(jbase + r) * 1024 + k0 + kg * 8;
            float4 a0 = *(const float4*)(xa);
            float4 a1 = *(const float4*)(xa + 4);
            float4 b0 = *(const float4*)(wb);
            float4 b1 = *(const float4*)(wb + 4);
            union { short8_t v; unsigned short u[8]; } ua, ub;
            float af[8] = {a0.x,a0.y,a0.z,a0.w,a1.x,a1.y,a1.z,a1.w};
            float bf[8] = {b0.x,b0.y,b0.z,b0.w,b1.x,b1.y,b1.z,b1.w};
#pragma unroll
            for (int e = 0; e < 8; ++e) {
                ua.u[e] = f2bf(af[e]);
                ub.u[e] = f2bf(bf[e]);
            }
            As[kg * 128 + r] = ua.v;
            Bs[kg * 128 + r] = ub.v;
        }
        __syncthreads();

        short8_t a[4], b[4];
#pragma unroll
        for (int mi = 0; mi < 4; ++mi)
            a[mi] = As[q * 128 + wm * 64 + mi * 16 + lr];
#pragma unroll
        for (int nj = 0; nj < 4; ++nj)
            b[nj] = Bs[q * 128 + wn * 64 + nj * 16 + lr];
#pragma unroll
        for (int mi = 0; mi < 4; ++mi)
#pragma unroll
            for (int nj = 0; nj < 4; ++nj)
                acc[mi][nj] = __builtin_amdgcn_mfma_f32_16x16x32_bf16(
                    a[mi], b[nj], acc[mi][nj], 0, 0, 0);
        __syncthreads();
    }

#pragma unroll
    for (int mi = 0; mi < 4; ++mi)
#pragma unroll
        for (int nj = 0; nj < 4; ++nj)
#pragma unroll
            for (int r = 0; r < 4; ++r) {
                int m = m0 + wm * 64 + mi * 16 + q * 4 + r;
                int n = bn * 128 + wn * 64 + nj * 16 + lr;
                int tt = m >> 6, bb = m & 63;
                int g = n >> 10, jc = n & 1023;
                xpf[(((size_t)tt * NBLK + (jc >> 3)) * 64 + bb) * 32 + (jc & 7) * 4 + g]
                    = f2bf(acc[mi][nj][r]);
            }
}

// ---------------------------------------------------------------------------
// Persistent MFMA LSTM loop. Round-13: (1) all 64 h-loads hoisted to one
// latency round; (2) per-wave flag polling (no post-poll syncthreads);
// (3) out store moved after the barrier (out of the drain path).
// ---------------------------------------------------------------------------
__global__ __launch_bounds__(512, 1) void lstm_loop11(
    const unsigned short* __restrict__ xpf,
    const unsigned short* __restrict__ PGh, const unsigned short* __restrict__ PGl,
    const unsigned short* __restrict__ POh, const unsigned short* __restrict__ POl,
    const float* __restrict__ c0,
    unsigned short* __restrict__ hA, unsigned short* __restrict__ hB,
    float* __restrict__ out,
    unsigned* __restrict__ bar)
{
    __shared__ f32x4 red[8][12][64];    // [wave][mt*3+nc][lane]  96 KB
    __shared__ f32x4 redF[12][64];      //                        12 KB

    const int tid  = threadIdx.x;
    const int lane = tid & 63;
    const int kq   = tid >> 6;
    const int ng   = blockIdx.x;        // 0..127

    // ---- persistent B fragments in registers ----
    short8_t bgh[2][4], bgl[2][4], boh[4], bol[4];
#pragma unroll
    for (int i = 0; i < 4; ++i) {
        int ks = 4 * kq + i;
#pragma unroll
        for (int nt = 0; nt < 2; ++nt) {
            size_t og = (((size_t)(ng * 2 + nt) * 32 + ks) * 64 + lane) * 8;
            bgh[nt][i] = *(const short8_t*)(PGh + og);
            bgl[nt][i] = *(const short8_t*)(PGl + og);
        }
        short8_t zh = {0,0,0,0,0,0,0,0};
        short8_t zl = {0,0,0,0,0,0,0,0};
        if ((lane & 15) < 8) {
            size_t oo = (((size_t)ng * 32 + ks) * 32 + (lane >> 4) * 8 + (lane & 7)) * 8;
            zh = *(const short8_t*)(POh + oo);
            zl = *(const short8_t*)(POl + oo);
        }
        boh[i] = zh; bol[i] = zl;
    }

    // combine identity: all 512 threads, b = tid>>3, jj = tid&7
    const int cb = tid >> 3, cjj = tid & 7;
    float c_reg = c0[(size_t)cb * 1024 + 8 * ng + cjj];
    ushort4_t xq = *(const ushort4_t*)(xpf + ((size_t)ng * 64 + cb) * 32 + cjj * 4);

    // h-store address pieces: j-range [8ng,8ng+8) = one full 8-elem k-group
    const int ks2  = ng >> 2;
    const int l2hi = (ng & 3) << 4;
    const unsigned hbase = ((((unsigned)(cb >> 4)) * 32 + ks2) * 64 + ((cb & 15) | l2hi)) * 8 + cjj;

    // flag replica this block polls
    unsigned* flagp = bar + 576 + (ng & 15) * 32;

#pragma unroll 1
    for (int t = 0; t <= T_STEPS; ++t) {
        const unsigned short* hc = (t & 1) ? hB : hA;
        unsigned short*       hn = (t & 1) ? hA : hB;

        // ---- hoisted h loads: all 4 k-groups x 4 m-tiles x hi/lo at once ----
        short8_t ah[4][4], al[4][4];
#pragma unroll
        for (int i = 0; i < 4; ++i) {
            const int ks = 4 * kq + i;
#pragma unroll
            for (int mt = 0; mt < 4; ++mt) {
                int off = ((mt * 32 + ks) * 64 + lane) * 8;
                union { short8_t v; unsigned long long q[2]; } uh, ul;
                const unsigned long long* ph = (const unsigned long long*)(hc + off);
                const unsigned long long* pl = (const unsigned long long*)(hc + 65536 + off);
                uh.q[0] = __hip_atomic_load(ph,     __ATOMIC_RELAXED, __HIP_MEMORY_SCOPE_SYSTEM);
                uh.q[1] = __hip_atomic_load(ph + 1, __ATOMIC_RELAXED, __HIP_MEMORY_SCOPE_SYSTEM);
                ul.q[0] = __hip_atomic_load(pl,     __ATOMIC_RELAXED, __HIP_MEMORY_SCOPE_SYSTEM);
                ul.q[1] = __hip_atomic_load(pl + 1, __ATOMIC_RELAXED, __HIP_MEMORY_SCOPE_SYSTEM);
                ah[i][mt] = uh.v;
                al[i][mt] = ul.v;
            }
        }

        f32x4 acc[4][3];
#pragma unroll
        for (int mt = 0; mt < 4; ++mt)
#pragma unroll
            for (int nc = 0; nc < 3; ++nc)
                acc[mt][nc] = (f32x4){0.f, 0.f, 0.f, 0.f};

#pragma unroll
        for (int i = 0; i < 4; ++i) {
#pragma unroll
            for (int mt = 0; mt < 4; ++mt) {
                acc[mt][0] = __builtin_amdgcn_mfma_f32_16x16x32_bf16(ah[i][mt], bgh[0][i], acc[mt][0], 0,0,0);
                acc[mt][1] = __builtin_amdgcn_mfma_f32_16x16x32_bf16(ah[i][mt], bgh[1][i], acc[mt][1], 0,0,0);
                acc[mt][2] = __builtin_amdgcn_mfma_f32_16x16x32_bf16(ah[i][mt], boh[i],    acc[mt][2], 0,0,0);
                acc[mt][0] = __builtin_amdgcn_mfma_f32_16x16x32_bf16(al[i][mt], bgh[0][i], acc[mt][0], 0,0,0);
                acc[mt][1] = __builtin_amdgcn_mfma_f32_16x16x32_bf16(al[i][mt], bgh[1][i], acc[mt][1], 0,0,0);
                acc[mt][2] = __builtin_amdgcn_mfma_f32_16x16x32_bf16(al[i][mt], boh[i],    acc[mt][2], 0,0,0);
                acc[mt][0] = __builtin_amdgcn_mfma_f32_16x16x32_bf16(ah[i][mt], bgl[0][i], acc[mt][0], 0,0,0);
                acc[mt][1] = __builtin_amdgcn_mfma_f32_16x16x32_bf16(ah[i][mt], bgl[1][i], acc[mt][1], 0,0,0);
                acc[mt][2] = __builtin_amdgcn_mfma_f32_16x16x32_bf16(ah[i][mt], bol[i],    acc[mt][2], 0,0,0);
            }
        }

        // ---- K-reduction across 8 waves (12 tiles) ----
#pragma unroll
        for (int mt = 0; mt < 4; ++mt)
#pragma unroll
            for (int nc = 0; nc < 3; ++nc)
                red[kq][mt * 3 + nc][lane] = acc[mt][nc];
        __syncthreads();
        {
            f32x4 s = red[0][kq][lane];
#pragma unroll
            for (int q = 1; q < 8; ++q) s += red[q][kq][lane];
            redF[kq][lane] = s;
        }
        if (kq < 4) {
            const int tl = 8 + kq;
            f32x4 s = red[0][tl][lane];
#pragma unroll
            for (int q = 1; q < 8; ++q) s += red[q][tl][lane];
            redF[tl][lane] = s;
        }
        __syncthreads();

        // ---- combine (all 512 threads): gates -> c,h (direct publish) ----
        float ov;
        {
            const int mt = cb >> 4;
            const int lnb = (cb & 12) << 2;
            const int rg = cb & 3;
            ov = redF[mt * 3 + 2][lnb | cjj][rg];
            if (t < T_STEPS) {
                const int nt = cjj >> 2;
                float pre0 = redF[mt * 3 + nt][lnb | (0  + (cjj & 3))][rg] + bf2f(xq[0]);
                float pre1 = redF[mt * 3 + nt][lnb | (4  + (cjj & 3))][rg] + bf2f(xq[1]);
                float pre2 = redF[mt * 3 + nt][lnb | (8  + (cjj & 3))][rg] + bf2f(xq[2]);
                float pre3 = redF[mt * 3 + nt][lnb | (12 + (cjj & 3))][rg] + bf2f(xq[3]);
                float gi = 1.f / (1.f + expf(-pre0));
                float gf = 1.f / (1.f + expf(-pre1));
                float go = 1.f / (1.f + expf(-pre2));
                float cn = gf * c_reg + gi * tanhf(pre3);
                c_reg = cn;
                float hv = go * tanhf(cn);
                unsigned short hhi = f2bf(hv);
                unsigned short hlo = f2bf(hv - bf2f(hhi));

                // pair-pack with neighbor lane (cjj+1) and publish directly
                unsigned hhiN = (unsigned short)__shfl_down((int)hhi, 1);
                unsigned hloN = (unsigned short)__shfl_down((int)hlo, 1);
                if ((cjj & 1) == 0) {
                    unsigned hp = (unsigned)hhi | (hhiN << 16);
                    unsigned lp = (unsigned)hlo | (hloN << 16);
                    __hip_atomic_store((unsigned*)(hn + hbase), hp,
                                       __ATOMIC_RELAXED, __HIP_MEMORY_SCOPE_SYSTEM);
                    __hip_atomic_store((unsigned*)(hn + hbase + 65536), lp,
                                       __ATOMIC_RELAXED, __HIP_MEMORY_SCOPE_SYSTEM);
                }
                if (t + 1 < T_STEPS)
                    xq = *(const ushort4_t*)(xpf +
                        (((size_t)(t + 1) * NBLK + ng) * 64 + cb) * 32 + cjj * 4);
            }
        }

        // ---- striped grid barrier: relaxed SYSTEM; per-wave flag polling ----
        if (t < T_STEPS) {
            __syncthreads();   // all waves' h stores drained before arrival
            const unsigned tgt = (unsigned)(t + 1);
            if (tid == 0) {
                unsigned* scnt = bar + (ng >> 3) * 32;            // 16 stripes
                unsigned old = __hip_atomic_fetch_add(scnt, 1u,
                                   __ATOMIC_RELAXED, __HIP_MEMORY_SCOPE_SYSTEM);
                if (old == 8u * tgt - 1u) {
                    unsigned om = __hip_atomic_fetch_add(bar + 512, 1u,
                                   __ATOMIC_RELAXED, __HIP_MEMORY_SCOPE_SYSTEM);
                    if (om == 16u * tgt - 1u) {
#pragma unroll
                        for (int f = 0; f < 16; ++f)
                            __hip_atomic_store(bar + 576 + f * 32, tgt,
                                   __ATOMIC_RELAXED, __HIP_MEMORY_SCOPE_SYSTEM);
                    }
                }
            }
            // every wave polls its replica; releases itself the moment it flips
            while (__hip_atomic_load(flagp, __ATOMIC_RELAXED, __HIP_MEMORY_SCOPE_SYSTEM) < tgt)
                __builtin_amdgcn_s_sleep(1);
        }

        // ---- out[t-1] write (post-barrier: out of the drain path) ----
        if (t > 0)
            out[(size_t)(t - 1) * 65536 + cb * 1024 + 8 * ng + cjj] = ov;
    }
}

// ---------------------------------------------------------------------------
extern "C" void kernel_launch(void* const* d_in, const int* in_sizes, int n_in,
                              void* d_out, int out_size, void* d_ws, size_t ws_size,
                              hipStream_t stream)
{
    const float* x    = (const float*)d_in[0];
    const float* h0   = (const float*)d_in[1];
    const float* c0   = (const float*)d_in[2];
    const float* Wxi  = (const float*)d_in[3];
    const float* Wxf  = (const float*)d_in[4];
    const float* Wxo  = (const float*)d_in[5];
    const float* Wxc  = (const float*)d_in[6];
    const float* Whi  = (const float*)d_in[7];
    const float* Whf  = (const float*)d_in[8];
    const float* Who  = (const float*)d_in[9];
    const float* Whc  = (const float*)d_in[10];
    const float* Wout = (const float*)d_in[11];
    float* out = (float*)d_out;

    const size_t PG_B  = (size_t)NBLK * 2 * 32 * 64 * 8 * 2;   //  8,388,608 each
    const size_t PO_B  = (size_t)NBLK * 32 * 32 * 8 * 2;       //  2,097,152 each
    const size_t HF_B  = (size_t)2 * 4 * 32 * 64 * 8 * 2;      //    262,144 each
    const size_t BAR_B = 8192;
    const size_t XPF_B = (size_t)T_STEPS * NBLK * 64 * 32 * 2; // 134,217,728

    char* ws = (char*)d_ws;
    unsigned short* PGh = (unsigned short*)ws;  ws += PG_B;
    unsigned short* PGl = (unsigned short*)ws;  ws += PG_B;
    unsigned short* POh = (unsigned short*)ws;  ws += PO_B;
    unsigned short* POl = (unsigned short*)ws;  ws += PO_B;
    unsigned short* hA  = (unsigned short*)ws;  ws += HF_B;
    unsigned short* hB  = (unsigned short*)ws;  ws += HF_B;
    unsigned*       bar = (unsigned*)ws;        ws += BAR_B;
    unsigned short* xpf = (unsigned short*)ws;  ws += XPF_B;

    hipMemsetAsync(bar, 0, BAR_B, stream);
    pack_gate<<<dim3(16, NBLK), 256, 0, stream>>>(Whi, Whf, Who, Whc, PGh, PGl);
    pack_out<<<dim3(4, NBLK), 256, 0, stream>>>(Wout, POh, POl);
    trans_h0f<<<dim3(64), 256, 0, stream>>>(h0, hA);
    xproj_mfma<<<dim3(128, 32), 256, 0, stream>>>(x, Wxi, Wxf, Wxo, Wxc, xpf);

    lstm_loop11<<<dim3(NBLK), dim3(512), 0, stream>>>(
        xpf, PGh, PGl, POh, POl, c0, hA, hB, out, bar);
}